// Round 7
// baseline (80.704 us; speedup 1.0000x reference)
//
#include <hip/hip_runtime.h>
#include <hip/hip_fp16.h>

// Problem constants: B=2, L=8192, D=1024, f32 in/out.
#define BB 2
#define LL 8192
#define DD 1024
#define NCF 128    // fine chunks of length 64
#define TF 64      // fine chunk length
#define JPB 2      // fine chunks per block (t-span 128)
#define DSPAN 256  // d-slice per block
#define NBLK ((DD / DSPAN) * (NCF / JPB) * BB)   // 4*64*2 = 512 blocks

// ph = exp(-(pr^2+pi^2)) * exp(i*atan2(pi,pr))
__device__ __forceinline__ void compute_ph(float pr, float pi, float& phr, float& phi) {
    float r2 = fmaf(pr, pr, pi * pi);
    float mag = expf(-r2);
    float r = sqrtf(r2);
    if (r > 1e-30f) {
        float inv = mag / r;
        phr = pr * inv;
        phi = pi * inv;
    } else {
        phr = mag;  // atan2(0,0)=0 -> phase 1+0i
        phi = 0.0f;
    }
}

// Single-pass fused kernel. Co-residency: 512 blocks, 64 KB LDS each ->
// exactly 2 blocks/CU on 256 CUs -> all resident -> barrier cannot deadlock.
// x is read from HBM exactly once (parked in LDS as fp16 for the replay).
__global__ __launch_bounds__(256) void k_fused(
    const float* __restrict__ x,
    const float* __restrict__ pr, const float* __restrict__ pi,
    const float* __restrict__ qr, const float* __restrict__ qi,
    const float* __restrict__ lr, const float* __restrict__ li,
    float2* __restrict__ partial,
    unsigned int* __restrict__ bar,
    float* __restrict__ out)
{
    const int tid = threadIdx.x;
    const int d   = blockIdx.x * DSPAN + tid;   // 256-d slice
    const int J   = blockIdx.y;                 // 0..63 -> fine chunks 2J, 2J+1
    const int b   = blockIdx.z;

    __shared__ __half xs[JPB * TF * DSPAN];     // 128 x 256 fp16 = 64 KB

    float phr, phi; compute_ph(pr[d], pi[d], phr, phi);
    const float qre = qr[d], qim = qi[d];

    const int jf0 = J * JPB;
    const size_t base = ((size_t)b * LL + (size_t)jf0 * TF) * DD + d;
    const float* xp = x + base;

    // ---- phase 1: stream x once; stash fp16 in LDS; two fine partials ----
    {
        float sr = 0.f, si = 0.f;
        #pragma unroll 16
        for (int t = 0; t < TF; ++t) {
            float xv = xp[(size_t)t * DD];
            xs[t * DSPAN + tid] = __float2half(xv);
            float nr = fmaf(phr, sr, fmaf(-phi, si, qre * xv));
            float ni = fmaf(phi, sr, fmaf(phr, si, qim * xv));
            sr = nr; si = ni;
        }
        partial[((size_t)b * NCF + jf0) * DD + d] = make_float2(sr, si);
        sr = 0.f; si = 0.f;
        #pragma unroll 16
        for (int t = TF; t < 2 * TF; ++t) {
            float xv = xp[(size_t)t * DD];
            xs[t * DSPAN + tid] = __float2half(xv);
            float nr = fmaf(phr, sr, fmaf(-phi, si, qre * xv));
            float ni = fmaf(phi, sr, fmaf(phr, si, qim * xv));
            sr = nr; si = ni;
        }
        partial[((size_t)b * NCF + jf0 + 1) * DD + d] = make_float2(sr, si);
    }

    // ---- grid barrier (device scope; proven functional in R5) ----
    __syncthreads();
    if (tid == 0) {
        __threadfence();   // release: partials visible device-wide
        __hip_atomic_fetch_add(bar, 1u, __ATOMIC_ACQ_REL, __HIP_MEMORY_SCOPE_AGENT);
        while (__hip_atomic_load(bar, __ATOMIC_ACQUIRE, __HIP_MEMORY_SCOPE_AGENT) < NBLK) {
            __builtin_amdgcn_s_sleep(4);
        }
        __threadfence();   // acquire
    }
    __syncthreads();

    // ---- phase 2: a = ph^TF (6 squarings); fold partials 0..jf0-1 ----
    float ar = phr, ai = phi;
    #pragma unroll
    for (int k = 0; k < 6; ++k) {
        float nr = ar * ar - ai * ai;
        float ni = 2.f * ar * ai;
        ar = nr; ai = ni;
    }

    float Sr = lr[d], Si = li[d];
    const float2* pb = partial + (size_t)b * NCF * DD + d;
    const int cnt = jf0;                        // uniform per block (<=126)
    for (int bs = 0; bs < cnt; bs += 16) {      // 16 loads in flight per round
        float2 buf[16];
        #pragma unroll
        for (int u = 0; u < 16; ++u) {
            int k = bs + u;
            buf[u] = (k < cnt) ? pb[(size_t)k * DD] : make_float2(0.f, 0.f);
        }
        #pragma unroll
        for (int u = 0; u < 16; ++u) {
            int k = bs + u;
            if (k < cnt) {
                float nr = fmaf(ar, Sr, fmaf(-ai, Si, buf[u].x));
                float ni = fmaf(ai, Sr, fmaf(ar, Si, buf[u].y));
                Sr = nr; Si = ni;
            }
        }
    }

    // ---- phase 3: replay 128 steps from LDS x; write-only HBM traffic ----
    float* op = out + base;
    #pragma unroll 16
    for (int t = 0; t < JPB * TF; ++t) {
        float xv = __half2float(xs[t * DSPAN + tid]);
        float nr = fmaf(phr, Sr, fmaf(-phi, Si, qre * xv));
        float ni = fmaf(phi, Sr, fmaf(phr, Si, qim * xv));
        Sr = nr; Si = ni;
        op[(size_t)t * DD] = nr;
    }
}

extern "C" void kernel_launch(void* const* d_in, const int* in_sizes, int n_in,
                              void* d_out, int out_size, void* d_ws, size_t ws_size,
                              hipStream_t stream) {
    const float* x  = (const float*)d_in[0];
    const float* pr = (const float*)d_in[1];
    const float* pi = (const float*)d_in[2];
    const float* qr = (const float*)d_in[3];
    const float* qi = (const float*)d_in[4];
    const float* lr = (const float*)d_in[5];
    const float* li = (const float*)d_in[6];
    float* out = (float*)d_out;

    unsigned int* bar = (unsigned int*)d_ws;             // 4 B counter
    float2* partial = (float2*)((char*)d_ws + 1024);     // BB*NCF*DD*8 = 2 MB

    // reset barrier counter every call (graph-capture-safe async memset)
    hipMemsetAsync(d_ws, 0, 64, stream);

    dim3 grid(DD / DSPAN, NCF / JPB, BB);   // 4 x 64 x 2 = 512 blocks
    k_fused<<<grid, 256, 0, stream>>>(x, pr, pi, qr, qi, lr, li, partial, bar, out);
}

// Round 8
// 54.229 us; speedup vs baseline: 1.4882x; 1.4882x over previous
//
#include <hip/hip_runtime.h>

// Problem constants: B=2, L=8192, D=1024, f32 in/out.
#define BB 2
#define LL 8192
#define DD 1024
#define NC 128        // time chunks
#define TT 64         // chunk length (2^6)
#define NPAIR (DD/2)  // 512 d-pairs; thread <-> d-pair (8 B/lane streams)

// ph = exp(-(pr^2+pi^2)) * exp(i*atan2(pi,pr))
__device__ __forceinline__ void compute_ph(float pr, float pi, float& phr, float& phi) {
    float r2 = fmaf(pr, pr, pi * pi);
    float mag = expf(-r2);
    float r = sqrtf(r2);
    if (r > 1e-30f) {
        float inv = mag / r;
        phr = pr * inv;
        phi = pi * inv;
    } else {
        phr = mag;  // atan2(0,0)=0 -> phase 1+0i
        phi = 0.0f;
    }
}

// Pass 1: zero-init chunk recurrence y; write Re(y) straight to out and the
// chunk-end state to partial. x is read from HBM exactly once, here.
__global__ __launch_bounds__(256) void k_pass1(
    const float* __restrict__ x,
    const float* __restrict__ pr, const float* __restrict__ pi,
    const float* __restrict__ qr, const float* __restrict__ qi,
    float4* __restrict__ partial,
    float* __restrict__ out)
{
    const int p = blockIdx.x * 256 + threadIdx.x;   // d-pair 0..511
    const int j = blockIdx.y;
    const int b = blockIdx.z;
    const int d0 = 2 * p, d1 = d0 + 1;

    float phr0, phi0, phr1, phi1;
    compute_ph(pr[d0], pi[d0], phr0, phi0);
    compute_ph(pr[d1], pi[d1], phr1, phi1);
    const float q0r = qr[d0], q0i = qi[d0], q1r = qr[d1], q1i = qi[d1];

    const size_t rowbase = (size_t)b * LL + (size_t)j * TT;
    const float2* xp = (const float2*)(x + rowbase * DD) + p;
    float2* op = (float2*)(out + rowbase * DD) + p;

    float sr0 = 0.f, si0 = 0.f, sr1 = 0.f, si1 = 0.f;
    #pragma unroll 16
    for (int t = 0; t < TT; ++t) {
        float2 xv = xp[(size_t)t * NPAIR];
        float nr0 = fmaf(phr0, sr0, fmaf(-phi0, si0, q0r * xv.x));
        float ni0 = fmaf(phi0, sr0, fmaf(phr0, si0, q0i * xv.x));
        float nr1 = fmaf(phr1, sr1, fmaf(-phi1, si1, q1r * xv.y));
        float ni1 = fmaf(phi1, sr1, fmaf(phr1, si1, q1i * xv.y));
        sr0 = nr0; si0 = ni0; sr1 = nr1; si1 = ni1;
        op[(size_t)t * NPAIR] = make_float2(nr0, nr1);
    }
    partial[((size_t)b * NC + j) * NPAIR + p] = make_float4(sr0, si0, sr1, si1);
}

// Pass 2: fold partials 0..j-1 (uniform trip count per block, 16-deep batched
// loads), then RMW out: out[t] += Re(S * ph^(t+1)). Touches only out+partials,
// which are L2/L3-resident from pass 1 -> HBM sees just the final out flush.
__global__ __launch_bounds__(256) void k_pass2(
    const float* __restrict__ pr, const float* __restrict__ pi,
    const float* __restrict__ lr, const float* __restrict__ li,
    const float4* __restrict__ partial,
    float* __restrict__ out)
{
    const int p = blockIdx.x * 256 + threadIdx.x;   // d-pair 0..511
    const int j = blockIdx.y;
    const int b = blockIdx.z;
    const int d0 = 2 * p, d1 = d0 + 1;

    float phr0, phi0, phr1, phi1;
    compute_ph(pr[d0], pi[d0], phr0, phi0);
    compute_ph(pr[d1], pi[d1], phr1, phi1);

    // a = ph^TT by repeated squaring (TT = 2^6)
    float a0r = phr0, a0i = phi0, a1r = phr1, a1i = phi1;
    #pragma unroll
    for (int k = 0; k < 6; ++k) {
        float n0r = a0r * a0r - a0i * a0i, n0i = 2.f * a0r * a0i;
        float n1r = a1r * a1r - a1i * a1i, n1i = 2.f * a1r * a1i;
        a0r = n0r; a0i = n0i; a1r = n1r; a1i = n1i;
    }

    // fold: S = last; S <- a*S + P_k for k = 0..j-1
    float S0r = lr[d0], S0i = li[d0], S1r = lr[d1], S1i = li[d1];
    const float4* pb = partial + (size_t)b * NC * NPAIR + p;
    for (int bs = 0; bs < j; bs += 16) {
        float4 buf[16];
        #pragma unroll
        for (int u = 0; u < 16; ++u) {
            int k = bs + u;
            int kc = (k < j) ? k : (j - 1);          // clamp: always a valid load
            buf[u] = pb[(size_t)kc * NPAIR];
        }
        #pragma unroll
        for (int u = 0; u < 16; ++u) {
            int k = bs + u;
            if (k < j) {                              // uniform per block
                float n0r = fmaf(a0r, S0r, fmaf(-a0i, S0i, buf[u].x));
                float n0i = fmaf(a0i, S0r, fmaf(a0r, S0i, buf[u].y));
                float n1r = fmaf(a1r, S1r, fmaf(-a1i, S1i, buf[u].z));
                float n1i = fmaf(a1i, S1r, fmaf(a1r, S1i, buf[u].w));
                S0r = n0r; S0i = n0i; S1r = n1r; S1i = n1i;
            }
        }
    }

    // w = S * ph  (so at local step t, w = S * ph^(t+1))
    float w0r = S0r * phr0 - S0i * phi0, w0i = S0r * phi0 + S0i * phr0;
    float w1r = S1r * phr1 - S1i * phi1, w1i = S1r * phi1 + S1i * phr1;

    const size_t rowbase = (size_t)b * LL + (size_t)j * TT;
    float2* op = (float2*)(out + rowbase * DD) + p;
    #pragma unroll 16
    for (int t = 0; t < TT; ++t) {
        float2 o = op[(size_t)t * NPAIR];
        o.x += w0r; o.y += w1r;
        op[(size_t)t * NPAIR] = o;
        float n0r = fmaf(w0r, phr0, -(w0i * phi0));
        float n0i = fmaf(w0r, phi0,  (w0i * phr0));
        float n1r = fmaf(w1r, phr1, -(w1i * phi1));
        float n1i = fmaf(w1r, phi1,  (w1i * phr1));
        w0r = n0r; w0i = n0i; w1r = n1r; w1i = n1i;
    }
}

extern "C" void kernel_launch(void* const* d_in, const int* in_sizes, int n_in,
                              void* d_out, int out_size, void* d_ws, size_t ws_size,
                              hipStream_t stream) {
    const float* x  = (const float*)d_in[0];
    const float* pr = (const float*)d_in[1];
    const float* pi = (const float*)d_in[2];
    const float* qr = (const float*)d_in[3];
    const float* qi = (const float*)d_in[4];
    const float* lr = (const float*)d_in[5];
    const float* li = (const float*)d_in[6];
    float* out = (float*)d_out;

    float4* partial = (float4*)d_ws;   // BB*NC*NPAIR float4 = 2 MB

    dim3 grid(NPAIR / 256, NC, BB);    // 2 x 128 x 2 = 512 blocks
    k_pass1<<<grid, 256, 0, stream>>>(x, pr, pi, qr, qi, partial, out);
    k_pass2<<<grid, 256, 0, stream>>>(pr, pi, lr, li, partial, out);
}